// Round 8
// baseline (906.526 us; speedup 1.0000x reference)
//
#include <hip/hip_runtime.h>

// LSTM: B=512, T=512, I=128, H=50, O=10, fp32.
// R12: lstm_rec — pin the hv read-cluster with sched_barrier(0).
//  Cycle account (R9/R11): 1125 cyc/step = ~470 modeled issue + ~650 ≈ 7x90
//  individually-exposed hv ds_read_b128 (VGPR=132 proves hv not resident;
//  the machine scheduler sinks each read to its use — R8's source-level
//  reorder was undone, identical VGPR/time).
//  Fix: 7 reads at loop bottom (after h write) + __builtin_amdgcn_sched_barrier(0)
//  — a compile-time region edge the scheduler can't cross. Reads issue as one
//  pipelined burst; single counted lgkmcnt at next iter's first dot2; values
//  live across the barrier force 28 VGPRs resident (success indicator: VGPR
//  ~160-170). sched_barrier is not a wait: pv 4-deep prefetch unaffected.
//  Launcher reverted to single lstm launch (R11 chunking was measurement-only,
//  cost +40us). xproj measured 80us / 2.15TB/s — left untouched.
//  Known fixed harness overhead ~130us (total - dispatches, invariant R5-R11).

#define BB 512
#define TT 512
#define II 128
#define HH 50
#define GG 200   // 4*H

typedef _Float16 half2v __attribute__((ext_vector_type(2)));
typedef _Float16 half4v __attribute__((ext_vector_type(4)));
typedef _Float16 half8v __attribute__((ext_vector_type(8)));
typedef float float4v __attribute__((ext_vector_type(4)));

#if defined(__has_builtin)
#if __has_builtin(__builtin_amdgcn_fdot2)
#define HAVE_FDOT2 1
#endif
#endif

__device__ __forceinline__ float fdot2f(half2v a, half2v b, float c) {
#ifdef HAVE_FDOT2
    return __builtin_amdgcn_fdot2(a, b, c, false);
#else
    return c + (float)a[0] * (float)b[0] + (float)a[1] * (float)b[1];
#endif
}

__device__ __forceinline__ float fsig(float x) {
    return 1.f / (1.f + __expf(-x));
}
__device__ __forceinline__ float ftanh(float x) {
    return 2.f * fsig(2.f * x) - 1.f;
}

// ---------------- Kernel 0: prep (once per launch) ----------------
// Gate permutation: gp = unit*4 + gate  <->  orig g = gate*50 + unit.
// wfrags: W_ih rows in PERMUTED order as f16 MFMA B-fragments
//         [nt 13][kc 4][lane 64][j 8]
// whh16:  W_hh rows padded to 56 f16, ORIGINAL order  [g 200][56]
// biasv:  b_ih + b_hh in PERMUTED order               [gp 200]
__global__ __launch_bounds__(256) void prep_kernel(
    const float* __restrict__ W_ih, const float* __restrict__ W_hh,
    const float* __restrict__ b_ih, const float* __restrict__ b_hh,
    _Float16* __restrict__ wfrags, _Float16* __restrict__ whh16,
    float* __restrict__ biasv)
{
    int idx = blockIdx.x * 256 + threadIdx.x;
    if (idx < 3328) {                       // 13*4*64 fragment slots
        int lane = idx & 63, kc = (idx >> 6) & 3, nt = idx >> 8;
        int gp = nt * 16 + (lane & 15);     // permuted gate index
        int k0 = kc * 32 + ((lane >> 4) & 3) * 8;
        half8v v;
        if (gp < GG) {
            int u = gp >> 2, j = gp & 3;
            const float* wr = W_ih + (size_t)(j * HH + u) * II + k0;
            #pragma unroll
            for (int q = 0; q < 8; ++q) v[q] = (_Float16)wr[q];
        } else {
            #pragma unroll
            for (int q = 0; q < 8; ++q) v[q] = (_Float16)0.f;
        }
        *(half8v*)(wfrags + (size_t)idx * 8) = v;
    } else if (idx < 3328 + 2800) {         // 200 rows * 14 quads
        int r = idx - 3328;
        int g = r / 14, j4 = r % 14;
        #pragma unroll
        for (int j = 0; j < 4; ++j) {
            int hidx = j4 * 4 + j;
            whh16[g * 56 + hidx] = (hidx < HH) ? (_Float16)W_hh[g * HH + hidx]
                                               : (_Float16)0.f;
        }
    } else if (idx < 3328 + 2800 + GG) {
        int gp = idx - 6128;
        int u = gp >> 2, j = gp & 3;
        biasv[gp] = b_ih[j * HH + u] + b_hh[j * HH + u];
    }
}

// ---------------- Kernel 1: xproj via MFMA, batch-per-block ----------------
// Block = batch b; loops ntile (=Tc/64) t-tiles. wfrags in LDS (staged once),
// A-fragments direct-to-register, next tile prefetched under MFMA.
__global__ __launch_bounds__(256) void xproj_mfma(
    const float* __restrict__ x, const _Float16* __restrict__ wfrags,
    const float* __restrict__ biasv, _Float16* __restrict__ xp16,
    int t0, int ntile)
{
    __shared__ __align__(16) _Float16 wflds[3328 * 8];   // 53248 B
    __shared__ __align__(16) _Float16 dtile[64 * GG];    // 25600 B
    __shared__ float blds[GG];                           // 800 B  -> 79.6 KB
    const int tid = threadIdx.x;
    const int b = blockIdx.x;
    const int w = tid >> 6, l = tid & 63;

    // Stage W_ih fragments (53KB) + bias once per block (linear b128, no conflicts).
    for (int s = tid; s < 3328; s += 256)
        *(float4v*)(wflds + (size_t)s * 8) = *(const float4v*)(wfrags + (size_t)s * 8);
    for (int s = tid; s < GG; s += 256) blds[s] = biasv[s];

    // Per-thread A-fragment source: row = w*16 + (l&15), 8-float chunk (l>>4)&3.
    const int row = w * 16 + (l & 15);
    const int kq = (l >> 4) & 3;
    const float* xbase = x + ((size_t)b * TT + (size_t)t0 + row) * II + kq * 8;

    // Prologue: tile 0 A-fragments (4 kc x 32B = 8 float4).
    float4 f0[4], f1[4];
    #pragma unroll
    for (int kc = 0; kc < 4; ++kc) {
        f0[kc] = *(const float4*)(xbase + kc * 32);
        f1[kc] = *(const float4*)(xbase + kc * 32 + 4);
    }
    __syncthreads();   // wflds/blds ready

    const int colb = l & 15, rq = l >> 4;

    for (int tt = 0; tt < ntile; ++tt) {
        // Convert this tile's A-regs to half8 fragments.
        half8v a[4];
        #pragma unroll
        for (int kc = 0; kc < 4; ++kc) {
            a[kc][0] = (_Float16)f0[kc].x; a[kc][1] = (_Float16)f0[kc].y;
            a[kc][2] = (_Float16)f0[kc].z; a[kc][3] = (_Float16)f0[kc].w;
            a[kc][4] = (_Float16)f1[kc].x; a[kc][5] = (_Float16)f1[kc].y;
            a[kc][6] = (_Float16)f1[kc].z; a[kc][7] = (_Float16)f1[kc].w;
        }
        // Prefetch next tile's A into regs; completes under MFMA phase.
        if (tt + 1 < ntile) {
            const float* xn = xbase + (size_t)(tt + 1) * 64 * II;
            #pragma unroll
            for (int kc = 0; kc < 4; ++kc) {
                f0[kc] = *(const float4*)(xn + kc * 32);
                f1[kc] = *(const float4*)(xn + kc * 32 + 4);
            }
        }

        float4v acc[13];
        #pragma unroll
        for (int nt = 0; nt < 13; ++nt) acc[nt] = (float4v){0.f, 0.f, 0.f, 0.f};
        #pragma unroll
        for (int kc = 0; kc < 4; ++kc) {
            #pragma unroll
            for (int nt = 0; nt < 13; ++nt) {
                half8v bf = *(const half8v*)(wflds + (size_t)(((nt * 4 + kc) * 64) + l) * 8);
                acc[nt] = __builtin_amdgcn_mfma_f32_16x16x32_f16(a[kc], bf, acc[nt], 0, 0, 0);
            }
        }

        // Protect dtile from previous tile's writeout readers, then restage.
        __syncthreads();
        #pragma unroll
        for (int nt = 0; nt < 13; ++nt) {
            int g = nt * 16 + colb;
            if (g < GG) {
                float bs = blds[g];
                #pragma unroll
                for (int reg = 0; reg < 4; ++reg)
                    dtile[(w * 16 + rq * 4 + reg) * GG + g] = (_Float16)(acc[nt][reg] + bs);
            }
        }
        __syncthreads();

        // Coalesced writeout: 64*200 f16 = 1600 x 16B contiguous.
        _Float16* outp = xp16 + ((size_t)b * ntile + tt) * 64 * GG;
        #pragma unroll
        for (int it = 0; it < 7; ++it) {
            int idx = it * 256 + tid;
            if (idx < 1600) {
                float4v v = *(const float4v*)(dtile + (size_t)idx * 8);
                *(float4v*)(outp + (size_t)idx * 8) = v;
            }
        }
    }
}

// ---------------- Kernel 2: recurrence (single wave, LDS weights) ---------
#define WSTR 58   // padded row stride in f16 (29 words -> coprime with 32 banks)

__global__
__attribute__((amdgpu_flat_work_group_size(64, 64)))
__attribute__((amdgpu_waves_per_eu(1, 1)))
void lstm_rec(
    const _Float16* __restrict__ xp16, const _Float16* __restrict__ whh16,
    float* __restrict__ hs, float* __restrict__ cs, int Tc, int first)
{
    __shared__ __align__(16) _Float16 wlds[GG * WSTR];   // 23.2 KB
    __shared__ __align__(16) _Float16 hbuf[64];
    const int b = blockIdx.x;
    const int k = threadIdx.x;
    const int kk = (k < HH) ? k : 0;

    // Stage W_hh (22.4 KB) into padded LDS: 1400 b128 slots, 22 per lane.
    for (int s = k; s < 1400; s += 64) {
        int g = s / 7, j = s % 7;
        float4v v = *(const float4v*)(whh16 + (size_t)g * 56 + j * 8);
        *(float4v*)(wlds + (size_t)g * WSTR + j * 8) = v;
    }

    float c = 0.f;
    _Float16 hinit = (_Float16)0.f;
    if (!first && k < HH) {
        c = cs[b * HH + k];
        hinit = (_Float16)hs[b * HH + k];
    }
    hbuf[k] = hinit;
    __syncthreads();   // staging + init visibility (once)

    // Hoisted weight loads: rows kk, kk+50, kk+100, kk+150 (7 b128 each).
    // waves_per_eu(1,1): 512-VGPR budget -> resident (R7+: VGPR>=132).
    float4v wr0[7], wr1[7], wr2[7], wr3[7];
    #pragma unroll
    for (int j = 0; j < 7; ++j) {
        wr0[j] = *(const float4v*)(wlds + (size_t)(kk      ) * WSTR + j * 8);
        wr1[j] = *(const float4v*)(wlds + (size_t)(kk +  50) * WSTR + j * 8);
        wr2[j] = *(const float4v*)(wlds + (size_t)(kk + 100) * WSTR + j * 8);
        wr3[j] = *(const float4v*)(wlds + (size_t)(kk + 150) * WSTR + j * 8);
    }

    // xp: [b][t][unit*4+gate] -> one 8B load per step, 4-deep prefetch.
    const _Float16* xpb = xp16 + (size_t)b * Tc * GG + kk * 4;
    half4v pv[4];
    #pragma unroll
    for (int d = 0; d < 4; ++d) {
        int td = (d < Tc) ? d : (Tc - 1);
        pv[d] = *(const half4v*)(xpb + (size_t)td * GG);
    }

    // Loop-carried h fragments: initial read; re-read at iteration bottom,
    // pinned there by sched_barrier(0).
    half8v hv[7];
    #pragma unroll
    for (int j = 0; j < 7; ++j) hv[j] = *(half8v*)(hbuf + j * 8);

    float hlast = 0.f;
    #pragma unroll 4
    for (int t = 0; t < Tc; ++t) {
        const int s = t & 3;
        half4v p = pv[s];
        float aI = (float)p[0];
        float aF = (float)p[1];
        float aG = (float)p[2];
        float aO = (float)p[3];

        // refill slot s for t+4; stays in flight (sched_barrier is not a wait)
        {
            int tn = t + 4; if (tn >= Tc) tn = Tc - 1;
            pv[s] = *(const half4v*)(xpb + (size_t)tn * GG);
        }

        #pragma unroll
        for (int j = 0; j < 7; ++j) {
            half2v* hp = (half2v*)&hv[j];
            const half2v* w0 = (const half2v*)&wr0[j];
            const half2v* w1 = (const half2v*)&wr1[j];
            const half2v* w2 = (const half2v*)&wr2[j];
            const half2v* w3 = (const half2v*)&wr3[j];
            #pragma unroll
            for (int q = 0; q < 4; ++q) {
                half2v hq = hp[q];
                aI = fdot2f(hq, w0[q], aI);
                aF = fdot2f(hq, w1[q], aF);
                aG = fdot2f(hq, w2[q], aG);
                aO = fdot2f(hq, w3[q], aO);
            }
        }
        float ii = fsig(aI), ff = fsig(aF), gg2 = ftanh(aG), oo = fsig(aO);
        c = ff * c + ii * gg2;
        float hn = oo * ftanh(c);

        // Unconditional write (lanes>=50 store finite dup of h_0; reads of
        // [50..55] hit zero weight cols). Then the clustered re-read, fenced
        // so the machine scheduler cannot sink the reads into the next
        // iteration's dot chain (the R9/R11 ~650cyc/step exposure).
        hbuf[k] = (_Float16)hn;
        #pragma unroll
        for (int j = 0; j < 7; ++j) hv[j] = *(half8v*)(hbuf + j * 8);
        __builtin_amdgcn_sched_barrier(0);

        hlast = hn;
    }
    if (k < HH) {
        hs[b * HH + k] = hlast;
        cs[b * HH + k] = c;
    }
}

// ---------------- Kernel 3: FC epilogue ----------------
__global__ __launch_bounds__(256) void fc_kernel(
    const float* __restrict__ hs, const float* __restrict__ W_fc,
    const float* __restrict__ b_fc, float* __restrict__ out)
{
    int idx = blockIdx.x * blockDim.x + threadIdx.x;   // 512*10
    if (idx < BB * 10) {
        int b = idx / 10, o = idx % 10;
        float a = b_fc[o];
        #pragma unroll
        for (int kx = 0; kx < HH; ++kx)
            a += hs[b * HH + kx] * W_fc[o * HH + kx];
        out[idx] = a;
    }
}

extern "C" void kernel_launch(void* const* d_in, const int* in_sizes, int n_in,
                              void* d_out, int out_size, void* d_ws, size_t ws_size,
                              hipStream_t stream)
{
    const float* x    = (const float*)d_in[0];
    const float* W_ih = (const float*)d_in[1];
    const float* W_hh = (const float*)d_in[2];
    const float* b_ih = (const float*)d_in[3];
    const float* b_hh = (const float*)d_in[4];
    const float* W_fc = (const float*)d_in[5];
    const float* b_fc = (const float*)d_in[6];
    float* out = (float*)d_out;
    char* wsb = (char*)d_ws;

    const size_t hs_b = (size_t)BB * HH * sizeof(float);        // 102400
    const size_t wfrags_b = (size_t)13 * 4 * 64 * 8 * 2;        // 53248
    const size_t whh_b = (size_t)GG * 56 * 2;                   // 22400
    const size_t bias_b = 1024;
    const size_t fixed_b = 2 * hs_b + wfrags_b + whh_b + bias_b;

    int Tc = TT;
    while (Tc > 64 && (size_t)BB * Tc * GG * 2 + fixed_b > ws_size)
        Tc >>= 1;

    _Float16* xp16 = (_Float16*)wsb;
    char* p = wsb + (size_t)BB * Tc * GG * 2;
    float* hsbuf = (float*)p;            p += hs_b;
    float* csbuf = (float*)p;            p += hs_b;
    _Float16* wfrags = (_Float16*)p;     p += wfrags_b;
    _Float16* whh16 = (_Float16*)p;      p += whh_b;
    float* biasv = (float*)p;

    prep_kernel<<<25, 256, 0, stream>>>(W_ih, W_hh, b_ih, b_hh, wfrags, whh16, biasv);

    const int nch = TT / Tc;
    for (int j = 0; j < nch; ++j) {
        xproj_mfma<<<BB, 256, 0, stream>>>(x, wfrags, biasv, xp16, j * Tc, Tc >> 6);
        lstm_rec<<<BB, 64, 0, stream>>>(xp16, whh16, hsbuf, csbuf, Tc, j == 0);
    }
    fc_kernel<<<(BB * 10 + 255) / 256, 256, 0, stream>>>(hsbuf, W_fc, b_fc, out);
}

// Round 9
// 885.732 us; speedup vs baseline: 1.0235x; 1.0235x over previous
//
#include <hip/hip_runtime.h>

// LSTM: B=512, T=512, I=128, H=50, O=10, fp32.
// R13: lstm_rec — take DS scheduling away from the compiler (inline asm).
//  Evidence: R9 = 1125 cyc/step = 405 issue (modeled 394: 112 dot2 + 10
//  trans@8cyc + misc) + ~720 stall. VGPR=132 leaves ~4 spare regs -> the 7
//  hv ds_read_b128 can never be concurrently in flight -> HW-serialized
//  ~100cyc each. Every compiler-steering attempt (R5 clobber, R8 order,
//  R10 readlane, R12 fence) hit ~700us or no-op; compiler's own schedule
//  is the 1125 attractor.
//  Fix: asm volatile ds_write_b16 + ONE asm with 7x ds_read_b128 ("=&v"
//  early-clobber: 28 VGPRs FORCED live, burst-issued, volatile-ordered
//  after the write; same-wave DS pipe in-order, proven R5-R12). Next iter:
//  xp unpack + refill first, then asm "s_waitcnt lgkmcnt(0)" +
//  sched_barrier(0) (rule-18 placement), then dots. Exposure ~100-150cyc
//  instead of ~720. Success indicator: VGPR ~160-170.
//  xproj (80us, measured R11) / prep / fc / launcher untouched.

#define BB 512
#define TT 512
#define II 128
#define HH 50
#define GG 200   // 4*H

typedef _Float16 half2v __attribute__((ext_vector_type(2)));
typedef _Float16 half4v __attribute__((ext_vector_type(4)));
typedef _Float16 half8v __attribute__((ext_vector_type(8)));
typedef float float4v __attribute__((ext_vector_type(4)));

#if defined(__has_builtin)
#if __has_builtin(__builtin_amdgcn_fdot2)
#define HAVE_FDOT2 1
#endif
#endif

__device__ __forceinline__ float fdot2f(half2v a, half2v b, float c) {
#ifdef HAVE_FDOT2
    return __builtin_amdgcn_fdot2(a, b, c, false);
#else
    return c + (float)a[0] * (float)b[0] + (float)a[1] * (float)b[1];
#endif
}

__device__ __forceinline__ float fsig(float x) {
    return 1.f / (1.f + __expf(-x));
}
__device__ __forceinline__ float ftanh(float x) {
    return 2.f * fsig(2.f * x) - 1.f;
}

// ---------------- Kernel 0: prep (once per launch) ----------------
__global__ __launch_bounds__(256) void prep_kernel(
    const float* __restrict__ W_ih, const float* __restrict__ W_hh,
    const float* __restrict__ b_ih, const float* __restrict__ b_hh,
    _Float16* __restrict__ wfrags, _Float16* __restrict__ whh16,
    float* __restrict__ biasv)
{
    int idx = blockIdx.x * 256 + threadIdx.x;
    if (idx < 3328) {                       // 13*4*64 fragment slots
        int lane = idx & 63, kc = (idx >> 6) & 3, nt = idx >> 8;
        int gp = nt * 16 + (lane & 15);     // permuted gate index
        int k0 = kc * 32 + ((lane >> 4) & 3) * 8;
        half8v v;
        if (gp < GG) {
            int u = gp >> 2, j = gp & 3;
            const float* wr = W_ih + (size_t)(j * HH + u) * II + k0;
            #pragma unroll
            for (int q = 0; q < 8; ++q) v[q] = (_Float16)wr[q];
        } else {
            #pragma unroll
            for (int q = 0; q < 8; ++q) v[q] = (_Float16)0.f;
        }
        *(half8v*)(wfrags + (size_t)idx * 8) = v;
    } else if (idx < 3328 + 2800) {         // 200 rows * 14 quads
        int r = idx - 3328;
        int g = r / 14, j4 = r % 14;
        #pragma unroll
        for (int j = 0; j < 4; ++j) {
            int hidx = j4 * 4 + j;
            whh16[g * 56 + hidx] = (hidx < HH) ? (_Float16)W_hh[g * HH + hidx]
                                               : (_Float16)0.f;
        }
    } else if (idx < 3328 + 2800 + GG) {
        int gp = idx - 6128;
        int u = gp >> 2, j = gp & 3;
        biasv[gp] = b_ih[j * HH + u] + b_hh[j * HH + u];
    }
}

// ---------------- Kernel 1: xproj via MFMA, batch-per-block ----------------
__global__ __launch_bounds__(256) void xproj_mfma(
    const float* __restrict__ x, const _Float16* __restrict__ wfrags,
    const float* __restrict__ biasv, _Float16* __restrict__ xp16,
    int t0, int ntile)
{
    __shared__ __align__(16) _Float16 wflds[3328 * 8];   // 53248 B
    __shared__ __align__(16) _Float16 dtile[64 * GG];    // 25600 B
    __shared__ float blds[GG];                           // 800 B  -> 79.6 KB
    const int tid = threadIdx.x;
    const int b = blockIdx.x;
    const int w = tid >> 6, l = tid & 63;

    for (int s = tid; s < 3328; s += 256)
        *(float4v*)(wflds + (size_t)s * 8) = *(const float4v*)(wfrags + (size_t)s * 8);
    for (int s = tid; s < GG; s += 256) blds[s] = biasv[s];

    const int row = w * 16 + (l & 15);
    const int kq = (l >> 4) & 3;
    const float* xbase = x + ((size_t)b * TT + (size_t)t0 + row) * II + kq * 8;

    float4 f0[4], f1[4];
    #pragma unroll
    for (int kc = 0; kc < 4; ++kc) {
        f0[kc] = *(const float4*)(xbase + kc * 32);
        f1[kc] = *(const float4*)(xbase + kc * 32 + 4);
    }
    __syncthreads();   // wflds/blds ready

    const int colb = l & 15, rq = l >> 4;

    for (int tt = 0; tt < ntile; ++tt) {
        half8v a[4];
        #pragma unroll
        for (int kc = 0; kc < 4; ++kc) {
            a[kc][0] = (_Float16)f0[kc].x; a[kc][1] = (_Float16)f0[kc].y;
            a[kc][2] = (_Float16)f0[kc].z; a[kc][3] = (_Float16)f0[kc].w;
            a[kc][4] = (_Float16)f1[kc].x; a[kc][5] = (_Float16)f1[kc].y;
            a[kc][6] = (_Float16)f1[kc].z; a[kc][7] = (_Float16)f1[kc].w;
        }
        if (tt + 1 < ntile) {
            const float* xn = xbase + (size_t)(tt + 1) * 64 * II;
            #pragma unroll
            for (int kc = 0; kc < 4; ++kc) {
                f0[kc] = *(const float4*)(xn + kc * 32);
                f1[kc] = *(const float4*)(xn + kc * 32 + 4);
            }
        }

        float4v acc[13];
        #pragma unroll
        for (int nt = 0; nt < 13; ++nt) acc[nt] = (float4v){0.f, 0.f, 0.f, 0.f};
        #pragma unroll
        for (int kc = 0; kc < 4; ++kc) {
            #pragma unroll
            for (int nt = 0; nt < 13; ++nt) {
                half8v bf = *(const half8v*)(wflds + (size_t)(((nt * 4 + kc) * 64) + l) * 8);
                acc[nt] = __builtin_amdgcn_mfma_f32_16x16x32_f16(a[kc], bf, acc[nt], 0, 0, 0);
            }
        }

        __syncthreads();
        #pragma unroll
        for (int nt = 0; nt < 13; ++nt) {
            int g = nt * 16 + colb;
            if (g < GG) {
                float bs = blds[g];
                #pragma unroll
                for (int reg = 0; reg < 4; ++reg)
                    dtile[(w * 16 + rq * 4 + reg) * GG + g] = (_Float16)(acc[nt][reg] + bs);
            }
        }
        __syncthreads();

        _Float16* outp = xp16 + ((size_t)b * ntile + tt) * 64 * GG;
        #pragma unroll
        for (int it = 0; it < 7; ++it) {
            int idx = it * 256 + tid;
            if (idx < 1600) {
                float4v v = *(const float4v*)(dtile + (size_t)idx * 8);
                *(float4v*)(outp + (size_t)idx * 8) = v;
            }
        }
    }
}

// ---------------- Kernel 2: recurrence (asm DS pipeline) -------------------
#define WSTR 58   // padded row stride in f16 (29 words -> coprime with 32 banks)

// Dot-group macro: 8 h values (as 4 half2 in one float4v) x 4 gates.
#define DOTG(HV, J)                                                   \
    {                                                                 \
        const half2v* hp = (const half2v*)&(HV);                      \
        const half2v* w0 = (const half2v*)&wr0[J];                    \
        const half2v* w1 = (const half2v*)&wr1[J];                    \
        const half2v* w2 = (const half2v*)&wr2[J];                    \
        const half2v* w3 = (const half2v*)&wr3[J];                    \
        _Pragma("unroll")                                             \
        for (int q = 0; q < 4; ++q) {                                 \
            half2v hq = hp[q];                                        \
            aI = fdot2f(hq, w0[q], aI);                               \
            aF = fdot2f(hq, w1[q], aF);                               \
            aG = fdot2f(hq, w2[q], aG);                               \
            aO = fdot2f(hq, w3[q], aO);                               \
        }                                                             \
    }

#define HV_READ()                                                     \
    asm volatile(                                                     \
        "ds_read_b128 %0, %7 offset:0\n\t"                            \
        "ds_read_b128 %1, %7 offset:16\n\t"                           \
        "ds_read_b128 %2, %7 offset:32\n\t"                           \
        "ds_read_b128 %3, %7 offset:48\n\t"                           \
        "ds_read_b128 %4, %7 offset:64\n\t"                           \
        "ds_read_b128 %5, %7 offset:80\n\t"                           \
        "ds_read_b128 %6, %7 offset:96"                               \
        : "=&v"(hv0), "=&v"(hv1), "=&v"(hv2), "=&v"(hv3),             \
          "=&v"(hv4), "=&v"(hv5), "=&v"(hv6)                          \
        : "v"(hraddr))

__global__
__attribute__((amdgpu_flat_work_group_size(64, 64)))
__attribute__((amdgpu_waves_per_eu(1, 1)))
void lstm_rec(
    const _Float16* __restrict__ xp16, const _Float16* __restrict__ whh16,
    float* __restrict__ hs, float* __restrict__ cs, int Tc, int first)
{
    __shared__ __align__(16) _Float16 wlds[GG * WSTR];   // 23.2 KB
    __shared__ __align__(16) _Float16 hbuf[64];
    const int b = blockIdx.x;
    const int k = threadIdx.x;
    const int kk = (k < HH) ? k : 0;

    // Stage W_hh (22.4 KB) into padded LDS.
    for (int s = k; s < 1400; s += 64) {
        int g = s / 7, j = s % 7;
        float4v v = *(const float4v*)(whh16 + (size_t)g * 56 + j * 8);
        *(float4v*)(wlds + (size_t)g * WSTR + j * 8) = v;
    }

    float c = 0.f;
    _Float16 hinit = (_Float16)0.f;
    if (!first && k < HH) {
        c = cs[b * HH + k];
        hinit = (_Float16)hs[b * HH + k];
    }
    hbuf[k] = hinit;
    __syncthreads();   // staging + init visibility (once)

    // Hoisted weight loads (resident since R7; VGPR>=132).
    float4v wr0[7], wr1[7], wr2[7], wr3[7];
    #pragma unroll
    for (int j = 0; j < 7; ++j) {
        wr0[j] = *(const float4v*)(wlds + (size_t)(kk      ) * WSTR + j * 8);
        wr1[j] = *(const float4v*)(wlds + (size_t)(kk +  50) * WSTR + j * 8);
        wr2[j] = *(const float4v*)(wlds + (size_t)(kk + 100) * WSTR + j * 8);
        wr3[j] = *(const float4v*)(wlds + (size_t)(kk + 150) * WSTR + j * 8);
    }

    // xp: [b][t][unit*4+gate] -> one 8B load per step, 4-deep prefetch.
    const _Float16* xpb = xp16 + (size_t)b * Tc * GG + kk * 4;
    half4v pv[4];
    #pragma unroll
    for (int d = 0; d < 4; ++d) {
        int td = (d < Tc) ? d : (Tc - 1);
        pv[d] = *(const half4v*)(xpb + (size_t)td * GG);
    }

    const unsigned hwaddr = (unsigned)(size_t)&hbuf[k];   // per-lane write slot
    const unsigned hraddr = (unsigned)(size_t)&hbuf[0];   // uniform read base

    // Initial broadcast read (hbuf valid after syncthreads); burst of 7,
    // early-clobber outputs force 28 live VGPRs.
    float4v hv0, hv1, hv2, hv3, hv4, hv5, hv6;
    HV_READ();

    float hlast = 0.f;
    #pragma unroll 4
    for (int t = 0; t < Tc; ++t) {
        const int s = t & 3;
        half4v p = pv[s];
        float aI = (float)p[0];
        float aF = (float)p[1];
        float aG = (float)p[2];
        float aO = (float)p[3];

        // refill slot s for t+4 BEFORE the lgkm wait (overlaps read latency)
        {
            int tn = t + 4; if (tn >= Tc) tn = Tc - 1;
            pv[s] = *(const half4v*)(xpb + (size_t)tn * GG);
        }

        // Rule-18 pattern: wait for the read burst issued at the previous
        // iteration's bottom, then fence so the compiler cannot hoist the
        // hv-consuming dots above the wait.
        asm volatile("s_waitcnt lgkmcnt(0)");
        __builtin_amdgcn_sched_barrier(0);

        DOTG(hv0, 0) DOTG(hv1, 1) DOTG(hv2, 2) DOTG(hv3, 3)
        DOTG(hv4, 4) DOTG(hv5, 5) DOTG(hv6, 6)

        float ii = fsig(aI), ff = fsig(aF), gg2 = ftanh(aG), oo = fsig(aO);
        c = ff * c + ii * gg2;
        float hn = oo * ftanh(c);

        // h broadcast: asm write then asm burst read (volatile-ordered;
        // same-wave DS pipe is in-order -> RAW safe). Lanes>=50 write a
        // finite dup of h_0; reads of slots 50..55 hit zero weight cols.
        unsigned hb = (unsigned)__builtin_bit_cast(unsigned short, (_Float16)hn);
        asm volatile("ds_write_b16 %0, %1" :: "v"(hwaddr), "v"(hb));
        HV_READ();

        hlast = hn;
    }
    // Drain the dangling final read burst before endpgm (asm ops are
    // invisible to the compiler's auto-waitcnt).
    asm volatile("s_waitcnt lgkmcnt(0)");

    if (k < HH) {
        hs[b * HH + k] = hlast;
        cs[b * HH + k] = c;
    }
}

// ---------------- Kernel 3: FC epilogue ----------------
__global__ __launch_bounds__(256) void fc_kernel(
    const float* __restrict__ hs, const float* __restrict__ W_fc,
    const float* __restrict__ b_fc, float* __restrict__ out)
{
    int idx = blockIdx.x * blockDim.x + threadIdx.x;   // 512*10
    if (idx < BB * 10) {
        int b = idx / 10, o = idx % 10;
        float a = b_fc[o];
        #pragma unroll
        for (int kx = 0; kx < HH; ++kx)
            a += hs[b * HH + kx] * W_fc[o * HH + kx];
        out[idx] = a;
    }
}

extern "C" void kernel_launch(void* const* d_in, const int* in_sizes, int n_in,
                              void* d_out, int out_size, void* d_ws, size_t ws_size,
                              hipStream_t stream)
{
    const float* x    = (const float*)d_in[0];
    const float* W_ih = (const float*)d_in[1];
    const float* W_hh = (const float*)d_in[2];
    const float* b_ih = (const float*)d_in[3];
    const float* b_hh = (const float*)d_in[4];
    const float* W_fc = (const float*)d_in[5];
    const float* b_fc = (const float*)d_in[6];
    float* out = (float*)d_out;
    char* wsb = (char*)d_ws;

    const size_t hs_b = (size_t)BB * HH * sizeof(float);        // 102400
    const size_t wfrags_b = (size_t)13 * 4 * 64 * 8 * 2;        // 53248
    const size_t whh_b = (size_t)GG * 56 * 2;                   // 22400
    const size_t bias_b = 1024;
    const size_t fixed_b = 2 * hs_b + wfrags_b + whh_b + bias_b;

    int Tc = TT;
    while (Tc > 64 && (size_t)BB * Tc * GG * 2 + fixed_b > ws_size)
        Tc >>= 1;

    _Float16* xp16 = (_Float16*)wsb;
    char* p = wsb + (size_t)BB * Tc * GG * 2;
    float* hsbuf = (float*)p;            p += hs_b;
    float* csbuf = (float*)p;            p += hs_b;
    _Float16* wfrags = (_Float16*)p;     p += wfrags_b;
    _Float16* whh16 = (_Float16*)p;      p += whh_b;
    float* biasv = (float*)p;

    prep_kernel<<<25, 256, 0, stream>>>(W_ih, W_hh, b_ih, b_hh, wfrags, whh16, biasv);

    const int nch = TT / Tc;
    for (int j = 0; j < nch; ++j) {
        xproj_mfma<<<BB, 256, 0, stream>>>(x, wfrags, biasv, xp16, j * Tc, Tc >> 6);
        lstm_rec<<<BB, 64, 0, stream>>>(xp16, whh16, hsbuf, csbuf, Tc, j == 0);
    }
    fc_kernel<<<(BB * 10 + 255) / 256, 256, 0, stream>>>(hsbuf, W_fc, b_fc, out);
}

// Round 10
// 434.830 us; speedup vs baseline: 2.0848x; 2.0370x over previous
//
#include <hip/hip_runtime.h>

// LSTM: B=512, T=512, I=128, H=50, O=10, fp32.
// R14: lstm_rec restructured — gate-per-lane, 4 waves per batch.
//  R5-R13 established: the unit-per-lane single-wave structure has a hard
//  floor at 1125 cyc/step (405 issue + serial chain with 1 wave/SIMD and
//  zero co-tenant; every fence attempt = 676-700us attractor, every
//  fence-free = 240us). Structure change:
//   - Block = 256 thr (4 waves), lane = gate gp=u*4+gate (200 active).
//   - Per lane: 28 dot2 (vs 112), ONE activation, then the unit's 4 gates
//     live in one QUAD -> 4x v_mov_dpp quad_perm broadcast (i,f,g,o) to all
//     quad lanes; c,h computed quad-redundantly; quad leader writes h.
//   - One __syncthreads per step republishes h (56-f16 hbuf, 7 b128 reads
//     broadcast to all lanes).
//   - Weights: 28 VGPRs/lane (7 b128 rows of whh16), loaded once.
//   - xp: one coalesced 2B global load/lane/step, depth-1 prefetch (the
//     per-step barrier drains vmcnt anyway; xp is L3-resident at 104MB).
//   - 512 blocks = 2 blocks/CU = 2 waves/SIMD -> co-scheduling hides
//     neighbor stalls (forbidden before by waves_per_eu(1,1)).
//  Per-wave issue ~135 cyc; chain ~330-400 -> predict 80-130us (was 240).
//  xproj (80us, R11-measured) / prep / fc untouched.

#define BB 512
#define TT 512
#define II 128
#define HH 50
#define GG 200   // 4*H

typedef _Float16 half2v __attribute__((ext_vector_type(2)));
typedef _Float16 half4v __attribute__((ext_vector_type(4)));
typedef _Float16 half8v __attribute__((ext_vector_type(8)));
typedef float float4v __attribute__((ext_vector_type(4)));

#if defined(__has_builtin)
#if __has_builtin(__builtin_amdgcn_fdot2)
#define HAVE_FDOT2 1
#endif
#endif

__device__ __forceinline__ float fdot2f(half2v a, half2v b, float c) {
#ifdef HAVE_FDOT2
    return __builtin_amdgcn_fdot2(a, b, c, false);
#else
    return c + (float)a[0] * (float)b[0] + (float)a[1] * (float)b[1];
#endif
}

__device__ __forceinline__ float fsig(float x) {
    return 1.f / (1.f + __expf(-x));
}
__device__ __forceinline__ float ftanh(float x) {
    return 2.f * fsig(2.f * x) - 1.f;
}

// ---------------- Kernel 0: prep (once per launch) ----------------
// Gate permutation: gp = unit*4 + gate  <->  orig g = gate*50 + unit.
// wfrags: W_ih rows in PERMUTED order as f16 MFMA B-fragments
// whh16:  W_hh rows padded to 56 f16, ORIGINAL order  [g 200][56]
// biasv:  b_ih + b_hh in PERMUTED order               [gp 200]
__global__ __launch_bounds__(256) void prep_kernel(
    const float* __restrict__ W_ih, const float* __restrict__ W_hh,
    const float* __restrict__ b_ih, const float* __restrict__ b_hh,
    _Float16* __restrict__ wfrags, _Float16* __restrict__ whh16,
    float* __restrict__ biasv)
{
    int idx = blockIdx.x * 256 + threadIdx.x;
    if (idx < 3328) {                       // 13*4*64 fragment slots
        int lane = idx & 63, kc = (idx >> 6) & 3, nt = idx >> 8;
        int gp = nt * 16 + (lane & 15);     // permuted gate index
        int k0 = kc * 32 + ((lane >> 4) & 3) * 8;
        half8v v;
        if (gp < GG) {
            int u = gp >> 2, j = gp & 3;
            const float* wr = W_ih + (size_t)(j * HH + u) * II + k0;
            #pragma unroll
            for (int q = 0; q < 8; ++q) v[q] = (_Float16)wr[q];
        } else {
            #pragma unroll
            for (int q = 0; q < 8; ++q) v[q] = (_Float16)0.f;
        }
        *(half8v*)(wfrags + (size_t)idx * 8) = v;
    } else if (idx < 3328 + 2800) {         // 200 rows * 14 quads
        int r = idx - 3328;
        int g = r / 14, j4 = r % 14;
        #pragma unroll
        for (int j = 0; j < 4; ++j) {
            int hidx = j4 * 4 + j;
            whh16[g * 56 + hidx] = (hidx < HH) ? (_Float16)W_hh[g * HH + hidx]
                                               : (_Float16)0.f;
        }
    } else if (idx < 3328 + 2800 + GG) {
        int gp = idx - 6128;
        int u = gp >> 2, j = gp & 3;
        biasv[gp] = b_ih[j * HH + u] + b_hh[j * HH + u];
    }
}

// ---------------- Kernel 1: xproj via MFMA, batch-per-block ----------------
__global__ __launch_bounds__(256) void xproj_mfma(
    const float* __restrict__ x, const _Float16* __restrict__ wfrags,
    const float* __restrict__ biasv, _Float16* __restrict__ xp16,
    int t0, int ntile)
{
    __shared__ __align__(16) _Float16 wflds[3328 * 8];   // 53248 B
    __shared__ __align__(16) _Float16 dtile[64 * GG];    // 25600 B
    __shared__ float blds[GG];                           // 800 B  -> 79.6 KB
    const int tid = threadIdx.x;
    const int b = blockIdx.x;
    const int w = tid >> 6, l = tid & 63;

    for (int s = tid; s < 3328; s += 256)
        *(float4v*)(wflds + (size_t)s * 8) = *(const float4v*)(wfrags + (size_t)s * 8);
    for (int s = tid; s < GG; s += 256) blds[s] = biasv[s];

    const int row = w * 16 + (l & 15);
    const int kq = (l >> 4) & 3;
    const float* xbase = x + ((size_t)b * TT + (size_t)t0 + row) * II + kq * 8;

    float4 f0[4], f1[4];
    #pragma unroll
    for (int kc = 0; kc < 4; ++kc) {
        f0[kc] = *(const float4*)(xbase + kc * 32);
        f1[kc] = *(const float4*)(xbase + kc * 32 + 4);
    }
    __syncthreads();   // wflds/blds ready

    const int colb = l & 15, rq = l >> 4;

    for (int tt = 0; tt < ntile; ++tt) {
        half8v a[4];
        #pragma unroll
        for (int kc = 0; kc < 4; ++kc) {
            a[kc][0] = (_Float16)f0[kc].x; a[kc][1] = (_Float16)f0[kc].y;
            a[kc][2] = (_Float16)f0[kc].z; a[kc][3] = (_Float16)f0[kc].w;
            a[kc][4] = (_Float16)f1[kc].x; a[kc][5] = (_Float16)f1[kc].y;
            a[kc][6] = (_Float16)f1[kc].z; a[kc][7] = (_Float16)f1[kc].w;
        }
        if (tt + 1 < ntile) {
            const float* xn = xbase + (size_t)(tt + 1) * 64 * II;
            #pragma unroll
            for (int kc = 0; kc < 4; ++kc) {
                f0[kc] = *(const float4*)(xn + kc * 32);
                f1[kc] = *(const float4*)(xn + kc * 32 + 4);
            }
        }

        float4v acc[13];
        #pragma unroll
        for (int nt = 0; nt < 13; ++nt) acc[nt] = (float4v){0.f, 0.f, 0.f, 0.f};
        #pragma unroll
        for (int kc = 0; kc < 4; ++kc) {
            #pragma unroll
            for (int nt = 0; nt < 13; ++nt) {
                half8v bf = *(const half8v*)(wflds + (size_t)(((nt * 4 + kc) * 64) + l) * 8);
                acc[nt] = __builtin_amdgcn_mfma_f32_16x16x32_f16(a[kc], bf, acc[nt], 0, 0, 0);
            }
        }

        __syncthreads();
        #pragma unroll
        for (int nt = 0; nt < 13; ++nt) {
            int g = nt * 16 + colb;
            if (g < GG) {
                float bs = blds[g];
                #pragma unroll
                for (int reg = 0; reg < 4; ++reg)
                    dtile[(w * 16 + rq * 4 + reg) * GG + g] = (_Float16)(acc[nt][reg] + bs);
            }
        }
        __syncthreads();

        _Float16* outp = xp16 + ((size_t)b * ntile + tt) * 64 * GG;
        #pragma unroll
        for (int it = 0; it < 7; ++it) {
            int idx = it * 256 + tid;
            if (idx < 1600) {
                float4v v = *(const float4v*)(dtile + (size_t)idx * 8);
                *(float4v*)(outp + (size_t)idx * 8) = v;
            }
        }
    }
}

// ---------------- Kernel 2: recurrence (gate-per-lane, 4 waves) ------------
__global__
__attribute__((amdgpu_flat_work_group_size(256, 256)))
__attribute__((amdgpu_waves_per_eu(1, 2)))
void lstm_rec(
    const _Float16* __restrict__ xp16, const _Float16* __restrict__ whh16,
    float* __restrict__ hs, float* __restrict__ cs, int Tc, int first)
{
    __shared__ __align__(16) _Float16 hbuf[56];   // 112 B: 50 h + 6 zero pad
    const int b = blockIdx.x;
    const int tid = threadIdx.x;
    // Lane = gate slot gp = u*4 + gate. Pad lanes (tid>=200) mirror gp=197
    // (unit 49, gate f): valid data, non-leader -> never write anything.
    const int gp = (tid < GG) ? tid : 197;
    const int u = gp >> 2;
    const int gate = gp & 3;
    const int wrow = gate * HH + u;               // original W_hh row order

    // Per-lane weight row: 7 x b128 = 28 VGPRs, one-time global load.
    float4v wv[7];
    #pragma unroll
    for (int j = 0; j < 7; ++j)
        wv[j] = *(const float4v*)(whh16 + (size_t)wrow * 56 + j * 8);

    // c replicated across the quad (each lane recomputes its unit's c).
    float c = (!first) ? cs[b * HH + u] : 0.f;

    // h buffer init: pads 50..55 stay zero forever (weights cols 50..55 = 0).
    if (tid < 56)
        hbuf[tid] = (tid < HH && !first) ? (_Float16)hs[b * HH + tid]
                                         : (_Float16)0.f;
    __syncthreads();

    // xp: [b][t][gp] -> one coalesced 2B load per lane per step.
    // Depth-1 prefetch: the per-step barrier drains vmcnt regardless, so the
    // load issued at step-top completes by the barrier (xp is L3-resident).
    const _Float16* xpb = xp16 + (size_t)b * Tc * GG + gp;
    _Float16 xpf = xpb[0];

    float hlast = 0.f;
    for (int t = 0; t < Tc; ++t) {
        // issue prefetch for t+1 (drained at this step's barrier)
        int tn = (t + 1 < Tc) ? t + 1 : t;
        _Float16 xnew = xpb[(size_t)tn * GG];

        // h broadcast read: 7 b128, same address all lanes (LDS broadcast).
        float4v hv[7];
        #pragma unroll
        for (int j = 0; j < 7; ++j) hv[j] = *(const float4v*)(hbuf + j * 8);

        // 28 dot2, 4-way split accumulators (dep chain 7 deep).
        float a0 = 0.f, a1 = 0.f, a2 = 0.f, a3 = 0.f;
        #pragma unroll
        for (int j = 0; j < 7; ++j) {
            const half2v* hp = (const half2v*)&hv[j];
            const half2v* wp = (const half2v*)&wv[j];
            a0 = fdot2f(hp[0], wp[0], a0);
            a1 = fdot2f(hp[1], wp[1], a1);
            a2 = fdot2f(hp[2], wp[2], a2);
            a3 = fdot2f(hp[3], wp[3], a3);
        }
        float acc = ((a0 + a1) + (a2 + a3)) + (float)xpf;

        // Activation: sigmoid for i,f,o; tanh for g (gate==2), branchless
        // via tanh(x) = 2*sigmoid(2x) - 1.
        bool isg = (gate == 2);
        float xin = isg ? 2.f * acc : acc;
        float sg = fsig(xin);
        float act = isg ? (2.f * sg - 1.f) : sg;

        // Quad broadcast: lanes u*4..u*4+3 hold (i,f,g,o) of unit u.
        int ai = __builtin_bit_cast(int, act);
        float gi = __builtin_bit_cast(float, __builtin_amdgcn_mov_dpp(ai, 0x00, 0xF, 0xF, true));
        float gf = __builtin_bit_cast(float, __builtin_amdgcn_mov_dpp(ai, 0x55, 0xF, 0xF, true));
        float gg = __builtin_bit_cast(float, __builtin_amdgcn_mov_dpp(ai, 0xAA, 0xF, 0xF, true));
        float go = __builtin_bit_cast(float, __builtin_amdgcn_mov_dpp(ai, 0xFF, 0xF, 0xF, true));

        c = gf * c + gi * gg;                 // quad-redundant, consistent
        float hn = go * ftanh(c);

        // Quad leader publishes h (50 writes total across the block).
        if (tid < GG && gate == 0) hbuf[u] = (_Float16)hn;
        __syncthreads();                      // republish h to all 4 waves

        xpf = xnew;
        hlast = hn;
    }

    if (tid < GG && gate == 0) {
        hs[b * HH + u] = hlast;
        cs[b * HH + u] = c;
    }
}

// ---------------- Kernel 3: FC epilogue ----------------
__global__ __launch_bounds__(256) void fc_kernel(
    const float* __restrict__ hs, const float* __restrict__ W_fc,
    const float* __restrict__ b_fc, float* __restrict__ out)
{
    int idx = blockIdx.x * blockDim.x + threadIdx.x;   // 512*10
    if (idx < BB * 10) {
        int b = idx / 10, o = idx % 10;
        float a = b_fc[o];
        #pragma unroll
        for (int kx = 0; kx < HH; ++kx)
            a += hs[b * HH + kx] * W_fc[o * HH + kx];
        out[idx] = a;
    }
}

extern "C" void kernel_launch(void* const* d_in, const int* in_sizes, int n_in,
                              void* d_out, int out_size, void* d_ws, size_t ws_size,
                              hipStream_t stream)
{
    const float* x    = (const float*)d_in[0];
    const float* W_ih = (const float*)d_in[1];
    const float* W_hh = (const float*)d_in[2];
    const float* b_ih = (const float*)d_in[3];
    const float* b_hh = (const float*)d_in[4];
    const float* W_fc = (const float*)d_in[5];
    const float* b_fc = (const float*)d_in[6];
    float* out = (float*)d_out;
    char* wsb = (char*)d_ws;

    const size_t hs_b = (size_t)BB * HH * sizeof(float);        // 102400
    const size_t wfrags_b = (size_t)13 * 4 * 64 * 8 * 2;        // 53248
    const size_t whh_b = (size_t)GG * 56 * 2;                   // 22400
    const size_t bias_b = 1024;
    const size_t fixed_b = 2 * hs_b + wfrags_b + whh_b + bias_b;

    int Tc = TT;
    while (Tc > 64 && (size_t)BB * Tc * GG * 2 + fixed_b > ws_size)
        Tc >>= 1;

    _Float16* xp16 = (_Float16*)wsb;
    char* p = wsb + (size_t)BB * Tc * GG * 2;
    float* hsbuf = (float*)p;            p += hs_b;
    float* csbuf = (float*)p;            p += hs_b;
    _Float16* wfrags = (_Float16*)p;     p += wfrags_b;
    _Float16* whh16 = (_Float16*)p;      p += whh_b;
    float* biasv = (float*)p;

    prep_kernel<<<25, 256, 0, stream>>>(W_ih, W_hh, b_ih, b_hh, wfrags, whh16, biasv);

    const int nch = TT / Tc;
    for (int j = 0; j < nch; ++j) {
        xproj_mfma<<<BB, 256, 0, stream>>>(x, wfrags, biasv, xp16, j * Tc, Tc >> 6);
        lstm_rec<<<BB, 256, 0, stream>>>(xp16, whh16, hsbuf, csbuf, Tc, j == 0);
    }
    fc_kernel<<<(BB * 10 + 255) / 256, 256, 0, stream>>>(hsbuf, W_fc, b_fc, out);
}